// Round 1
// baseline (885.109 us; speedup 1.0000x reference)
//
#include <hip/hip_runtime.h>

#define N_NODES 8192
#define F_DIM 512
#define K_HEADS 2
#define O_DIM 64
#define EDGE_CAP (2*1024*1024)

// merge two online-softmax states (m, s) -> (max, rescaled sum)
__device__ __forceinline__ void smax_merge(float& m, float& s, float mo, float so) {
  float M = fmaxf(m, mo);
  if (M == -INFINITY) { m = -INFINITY; s = 0.f; return; }
  s = s * __expf(m - M) + so * __expf(mo - M);
  m = M;
}

// K1: HW[k,n,o] = sum_f H[n,f] W[k,f,o];  c1[k,n]=HW.a1, c2[k,n]=HW.a2
// grid 512 (k = b&1, 32 rows per block), block 256 = 4 waves x 8 rows, lane = o
__global__ __launch_bounds__(256) void k1_hw(
    const float* __restrict__ H, const float* __restrict__ W,
    const float* __restrict__ a1, const float* __restrict__ a2,
    float* __restrict__ HW, float* __restrict__ c1, float* __restrict__ c2) {
  const int k    = blockIdx.x & 1;
  const int wv   = threadIdx.x >> 6;
  const int lane = threadIdx.x & 63;
  const int nbase = __builtin_amdgcn_readfirstlane((blockIdx.x >> 1) * 32 + wv * 8);
  const float* __restrict__ Wk = W + k * (F_DIM * O_DIM);
  float acc[8] = {0.f,0.f,0.f,0.f,0.f,0.f,0.f,0.f};
  for (int f = 0; f < F_DIM; f += 4) {
    float w0 = Wk[(f+0)*64 + lane];
    float w1 = Wk[(f+1)*64 + lane];
    float w2 = Wk[(f+2)*64 + lane];
    float w3 = Wk[(f+3)*64 + lane];
#pragma unroll
    for (int r = 0; r < 8; ++r) {
      float4 h = *(const float4*)(H + (size_t)(nbase + r) * F_DIM + f);  // wave-uniform -> s_load
      acc[r] = fmaf(h.x, w0, acc[r]);
      acc[r] = fmaf(h.y, w1, acc[r]);
      acc[r] = fmaf(h.z, w2, acc[r]);
      acc[r] = fmaf(h.w, w3, acc[r]);
    }
  }
  const float a1v = a1[k*64 + lane];
  const float a2v = a2[k*64 + lane];
#pragma unroll
  for (int r = 0; r < 8; ++r) {
    const int n = nbase + r;
    HW[((size_t)k * N_NODES + n) * 64 + lane] = acc[r];
    float t1 = acc[r] * a1v;
    float t2 = acc[r] * a2v;
#pragma unroll
    for (int off = 32; off > 0; off >>= 1) {
      t1 += __shfl_down(t1, off);
      t2 += __shfl_down(t2, off);
    }
    if (lane == 0) {
      c1[k * N_NODES + n] = t1;
      c2[k * N_NODES + n] = t2;
    }
  }
}

// K2: one block per row j. Single dense scan of A: online softmax stats per (k,j),
// ballot bitmask (row-major), per-column edge counts (atomics).
__global__ __launch_bounds__(256) void k2_stats(
    const float* __restrict__ A, const int* __restrict__ idx,
    const float* __restrict__ c1, const float* __restrict__ c2,
    unsigned long long* __restrict__ mask, int* __restrict__ colcnt,
    float4* __restrict__ param) {
  __shared__ int sidx[N_NODES];
  __shared__ float redm[2][4], reds[2][4];
  const int j = blockIdx.x;
  const int tid = threadIdx.x;
  const int wv = tid >> 6, lane = tid & 63;
  for (int t = tid; t < N_NODES/4; t += 256)
    ((int4*)sidx)[t] = ((const int4*)idx)[t];
  __syncthreads();
  const float c10 = c1[j];
  const float c11 = c1[N_NODES + j];
  const float* __restrict__ Arow = A + (size_t)j * N_NODES;
  float m0 = -INFINITY, s0 = 0.f, m1 = -INFINITY, s1 = 0.f;
  for (int seg = 0; seg < 32; ++seg) {
    const int i = seg * 256 + tid;
    const int col = sidx[i];
    const float a = Arow[col];
    const bool pred = (a != 0.f);
    unsigned long long bal = __ballot(pred);
    if (lane == 0) mask[(size_t)j * 128 + seg * 4 + wv] = bal;
    if (pred) {
      atomicAdd(&colcnt[i], 1);
      float v0 = c10 + c2[i];
      v0 = (v0 >= 0.f) ? v0 : 0.2f * v0;
      if (v0 > m0) { s0 = s0 * __expf(m0 - v0) + 1.f; m0 = v0; }
      else         { s0 += __expf(v0 - m0); }
      float v1 = c11 + c2[N_NODES + i];
      v1 = (v1 >= 0.f) ? v1 : 0.2f * v1;
      if (v1 > m1) { s1 = s1 * __expf(m1 - v1) + 1.f; m1 = v1; }
      else         { s1 += __expf(v1 - m1); }
    }
  }
#pragma unroll
  for (int off = 32; off > 0; off >>= 1) {
    float mo = __shfl_down(m0, off), so = __shfl_down(s0, off);
    smax_merge(m0, s0, mo, so);
    mo = __shfl_down(m1, off); so = __shfl_down(s1, off);
    smax_merge(m1, s1, mo, so);
  }
  if (lane == 0) { redm[0][wv] = m0; reds[0][wv] = s0; redm[1][wv] = m1; reds[1][wv] = s1; }
  __syncthreads();
  if (tid == 0) {
    float M0 = redm[0][0], S0 = reds[0][0];
    float M1 = redm[1][0], S1 = reds[1][0];
#pragma unroll
    for (int w = 1; w < 4; ++w) {
      smax_merge(M0, S0, redm[0][w], reds[0][w]);
      smax_merge(M1, S1, redm[1][w], reds[1][w]);
    }
    float I0, I1;
    if (S0 > 0.f) { I0 = 1.f / S0; } else { I0 = 0.f; M0 = 0.f; }
    if (S1 > 0.f) { I1 = 1.f / S1; } else { I1 = 0.f; M1 = 0.f; }
    param[j]           = make_float4(c10, M0, I0, 0.f);
    param[N_NODES + j] = make_float4(c11, M1, I1, 0.f);
  }
}

// exclusive prefix sum over 8192 column counts -> colptr, cursor
__global__ __launch_bounds__(256) void k_scan(
    const int* __restrict__ colcnt, int* __restrict__ colptr, int* __restrict__ cursor) {
  __shared__ int ssum[256];
  const int t = threadIdx.x;
  const int base = t * 32;
  int loc[32];
  int run = 0;
#pragma unroll
  for (int r = 0; r < 32; ++r) { loc[r] = run; run += colcnt[base + r]; }
  ssum[t] = run;
  __syncthreads();
  for (int d = 1; d < 256; d <<= 1) {
    int v = (t >= d) ? ssum[t - d] : 0;
    __syncthreads();
    ssum[t] += v;
    __syncthreads();
  }
  const int inc = ssum[t];
  const int ex = inc - run;
#pragma unroll
  for (int r = 0; r < 32; ++r) {
    int p = ex + loc[r];
    colptr[base + r] = p;
    cursor[base + r] = p;
  }
  if (t == 255) colptr[N_NODES] = inc;
}

// fill CSC edge list from the bitmask. grid (128 col-tiles, 16 j-chunks), block = 1 wave
__global__ __launch_bounds__(64) void k_fill(
    const unsigned long long* __restrict__ mask,
    int* __restrict__ cursor, int* __restrict__ edges) {
  const int w = blockIdx.x;
  const int lane = threadIdx.x;
  const int i = w * 64 + lane;
  const int jbeg = blockIdx.y * 512;
  for (int jb = jbeg; jb < jbeg + 512; jb += 64) {
    unsigned long long mw_l = mask[(size_t)(jb + lane) * 128 + w];
    unsigned long long act = __ballot(mw_l != 0ULL);
    while (act) {
      int jj = __builtin_ctzll(act);
      act &= act - 1;
      unsigned long long mw = __shfl(mw_l, jj);
      if ((mw >> lane) & 1ULL) {
        int pos = atomicAdd(&cursor[i], 1);
        edges[pos] = jb + jj;
      }
    }
  }
}

// K3: one wave per output row i (lane = o). Gather neighbors j from CSC,
// w = exp(leaky(c1_j + c2_i) - m_j) / l_j ; acc += w * HW[j,:]. Fused bias+ReLU+transpose.
__global__ __launch_bounds__(256) void k3_aggregate(
    const int* __restrict__ colptr, const int* __restrict__ edges,
    const float4* __restrict__ param, const float* __restrict__ c2,
    const float* __restrict__ HW, const float* __restrict__ b,
    float* __restrict__ out) {
  const int lane = threadIdx.x & 63;
  const int i = __builtin_amdgcn_readfirstlane(blockIdx.x * 4 + (threadIdx.x >> 6));
  const float c20 = c2[i];
  const float c21 = c2[N_NODES + i];
  int e = colptr[i];
  const int end = colptr[i + 1];
  float acc0 = 0.f, acc1 = 0.f;
  for (; e < end; ++e) {
    const int j = edges[e];
    const float4 p0 = param[j];
    const float4 p1 = param[N_NODES + j];
    float v0 = p0.x + c20; v0 = (v0 >= 0.f) ? v0 : 0.2f * v0;
    float w0 = __expf(v0 - p0.y) * p0.z;
    float v1 = p1.x + c21; v1 = (v1 >= 0.f) ? v1 : 0.2f * v1;
    float w1 = __expf(v1 - p1.y) * p1.z;
    const float hw0 = HW[(size_t)j * 64 + lane];
    const float hw1 = HW[(size_t)(N_NODES + j) * 64 + lane];
    acc0 = fmaf(w0, hw0, acc0);
    acc1 = fmaf(w1, hw1, acc1);
  }
  float r0 = fmaxf(acc0 + b[lane], 0.f);
  float r1 = fmaxf(acc1 + b[64 + lane], 0.f);
  out[(size_t)i * 128 + lane]      = r0;
  out[(size_t)i * 128 + 64 + lane] = r1;
}

extern "C" void kernel_launch(void* const* d_in, const int* in_sizes, int n_in,
                              void* d_out, int out_size, void* d_ws, size_t ws_size,
                              hipStream_t stream) {
  const float* H   = (const float*)d_in[0];
  const float* A   = (const float*)d_in[1];
  const int*   idx = (const int*)d_in[2];
  const float* W   = (const float*)d_in[3];
  const float* b   = (const float*)d_in[4];
  const float* a1  = (const float*)d_in[5];
  const float* a2  = (const float*)d_in[6];
  float* out = (float*)d_out;

  char* ws = (char*)d_ws;
  // workspace layout (all offsets 256B aligned), total ~20.5 MiB
  float*              HW     = (float*)(ws + 0);                    //  4,194,304 B
  float*              c1     = (float*)(ws + 4194304);              //     65,536 B
  float*              c2     = (float*)(ws + 4259840);              //     65,536 B
  float4*             param  = (float4*)(ws + 4325376);             //    262,144 B
  unsigned long long* mask   = (unsigned long long*)(ws + 4587520); //  8,388,608 B
  int*                colcnt = (int*)(ws + 12976128);               //     32,768 B
  int*                colptr = (int*)(ws + 13008896);               //     36,864 B (8193 ints)
  int*                cursor = (int*)(ws + 13045760);               //     32,768 B
  int*                edges  = (int*)(ws + 13078528);               //  8,388,608 B (2M cap)

  hipMemsetAsync(colcnt, 0, N_NODES * sizeof(int), stream);
  k1_hw<<<512, 256, 0, stream>>>(H, W, a1, a2, HW, c1, c2);
  k2_stats<<<N_NODES, 256, 0, stream>>>(A, idx, c1, c2, mask, colcnt, param);
  k_scan<<<1, 256, 0, stream>>>(colcnt, colptr, cursor);
  k_fill<<<dim3(128, 16), 64, 0, stream>>>(mask, cursor, edges);
  k3_aggregate<<<N_NODES / 4, 256, 0, stream>>>(colptr, edges, param, c2, HW, b, out);
}

// Round 2
// 659.244 us; speedup vs baseline: 1.3426x; 1.3426x over previous
//
#include <hip/hip_runtime.h>

#define N_NODES 8192
#define F_DIM 512
#define K_HEADS 2
#define O_DIM 64

// merge two online-softmax states (m, s) -> (max, rescaled sum)
__device__ __forceinline__ void smax_merge(float& m, float& s, float mo, float so) {
  float M = fmaxf(m, mo);
  if (M == -INFINITY) { m = -INFINITY; s = 0.f; return; }
  s = s * __expf(m - M) + so * __expf(mo - M);
  m = M;
}

// K1: HW[k,n,o] = sum_f H[n,f] W[k,f,o];  c1[k,n]=HW.a1, c2[k,n]=HW.a2
__global__ __launch_bounds__(256) void k1_hw(
    const float* __restrict__ H, const float* __restrict__ W,
    const float* __restrict__ a1, const float* __restrict__ a2,
    float* __restrict__ HW, float* __restrict__ c1, float* __restrict__ c2) {
  const int k    = blockIdx.x & 1;
  const int wv   = threadIdx.x >> 6;
  const int lane = threadIdx.x & 63;
  const int nbase = __builtin_amdgcn_readfirstlane((blockIdx.x >> 1) * 32 + wv * 8);
  const float* __restrict__ Wk = W + k * (F_DIM * O_DIM);
  float acc[8] = {0.f,0.f,0.f,0.f,0.f,0.f,0.f,0.f};
  for (int f = 0; f < F_DIM; f += 4) {
    float w0 = Wk[(f+0)*64 + lane];
    float w1 = Wk[(f+1)*64 + lane];
    float w2 = Wk[(f+2)*64 + lane];
    float w3 = Wk[(f+3)*64 + lane];
#pragma unroll
    for (int r = 0; r < 8; ++r) {
      float4 h = *(const float4*)(H + (size_t)(nbase + r) * F_DIM + f);  // wave-uniform -> s_load
      acc[r] = fmaf(h.x, w0, acc[r]);
      acc[r] = fmaf(h.y, w1, acc[r]);
      acc[r] = fmaf(h.z, w2, acc[r]);
      acc[r] = fmaf(h.w, w3, acc[r]);
    }
  }
  const float a1v = a1[k*64 + lane];
  const float a2v = a2[k*64 + lane];
#pragma unroll
  for (int r = 0; r < 8; ++r) {
    const int n = nbase + r;
    HW[((size_t)k * N_NODES + n) * 64 + lane] = acc[r];
    float t1 = acc[r] * a1v;
    float t2 = acc[r] * a2v;
#pragma unroll
    for (int off = 32; off > 0; off >>= 1) {
      t1 += __shfl_down(t1, off);
      t2 += __shfl_down(t2, off);
    }
    if (lane == 0) {
      c1[k * N_NODES + n] = t1;
      c2[k * N_NODES + n] = t2;
    }
  }
}

// K2: 8 rows per block (grid 1024). Each thread owns a 32-column window.
// idx-contiguity checked ONCE (idx is row-invariant); fast path = 8 independent
// float4 loads of A per row. Produces: umask[j*256+t] (coalesced uint32 bitmask),
// per-column edge counts (atomics), per-(k,row) online-softmax params.
__global__ __launch_bounds__(256) void k2_stats(
    const float* __restrict__ A, const int* __restrict__ idx,
    const float* __restrict__ c1, const float* __restrict__ c2,
    unsigned* __restrict__ umask, int* __restrict__ colcnt,
    float4* __restrict__ param) {
  __shared__ float redm[2][4], reds[2][4];
  const int tid = threadIdx.x;
  const int wv = tid >> 6, lane = tid & 63;
  const int i0 = tid * 32;
  const int j0 = blockIdx.x * 8;

  // one-time contiguity + alignment check of this thread's idx window
  int base;
  bool fast;
  {
    int4 v0 = *(const int4*)(idx + i0);
    base = v0.x;
    fast = ((base & 3) == 0) && (v0.y == base+1) && (v0.z == base+2) && (v0.w == base+3);
#pragma unroll
    for (int g = 1; g < 8; ++g) {
      int4 v = *(const int4*)(idx + i0 + 4*g);
      fast = fast && (v.x == base+4*g) && (v.y == base+4*g+1) &&
                     (v.z == base+4*g+2) && (v.w == base+4*g+3);
    }
  }

  for (int r = 0; r < 8; ++r) {
    const int j = j0 + r;
    const float c10 = c1[j];
    const float c11 = c1[N_NODES + j];
    const float* __restrict__ Arow = A + (size_t)j * N_NODES;
    float4 a[8];
    if (fast) {
      const float* p = Arow + base;
#pragma unroll
      for (int g = 0; g < 8; ++g) a[g] = *(const float4*)(p + 4*g);
    } else {
#pragma unroll
      for (int g = 0; g < 8; ++g) {
        a[g].x = Arow[idx[i0 + 4*g + 0]];
        a[g].y = Arow[idx[i0 + 4*g + 1]];
        a[g].z = Arow[idx[i0 + 4*g + 2]];
        a[g].w = Arow[idx[i0 + 4*g + 3]];
      }
    }
    unsigned m32 = 0;
#pragma unroll
    for (int g = 0; g < 8; ++g) {
      m32 |= (a[g].x != 0.f ? 1u : 0u) << (4*g + 0);
      m32 |= (a[g].y != 0.f ? 1u : 0u) << (4*g + 1);
      m32 |= (a[g].z != 0.f ? 1u : 0u) << (4*g + 2);
      m32 |= (a[g].w != 0.f ? 1u : 0u) << (4*g + 3);
    }
    umask[(size_t)j * 256 + tid] = m32;

    float m0 = -INFINITY, s0 = 0.f, m1 = -INFINITY, s1 = 0.f;
    unsigned mm = m32;
    while (mm) {
      const int bpos = __builtin_ctz(mm);
      mm &= mm - 1;
      const int i = i0 + bpos;
      atomicAdd(&colcnt[i], 1);
      float v0 = c10 + c2[i];
      v0 = (v0 >= 0.f) ? v0 : 0.2f * v0;
      if (v0 > m0) { s0 = s0 * __expf(m0 - v0) + 1.f; m0 = v0; }
      else         { s0 += __expf(v0 - m0); }
      float v1 = c11 + c2[N_NODES + i];
      v1 = (v1 >= 0.f) ? v1 : 0.2f * v1;
      if (v1 > m1) { s1 = s1 * __expf(m1 - v1) + 1.f; m1 = v1; }
      else         { s1 += __expf(v1 - m1); }
    }
    // block reduction for row j
#pragma unroll
    for (int off = 32; off > 0; off >>= 1) {
      float mo = __shfl_down(m0, off), so = __shfl_down(s0, off);
      smax_merge(m0, s0, mo, so);
      mo = __shfl_down(m1, off); so = __shfl_down(s1, off);
      smax_merge(m1, s1, mo, so);
    }
    if (lane == 0) { redm[0][wv] = m0; reds[0][wv] = s0; redm[1][wv] = m1; reds[1][wv] = s1; }
    __syncthreads();
    if (tid == 0) {
      float M0 = redm[0][0], S0 = reds[0][0];
      float M1 = redm[1][0], S1 = reds[1][0];
#pragma unroll
      for (int w = 1; w < 4; ++w) {
        smax_merge(M0, S0, redm[0][w], reds[0][w]);
        smax_merge(M1, S1, redm[1][w], reds[1][w]);
      }
      float I0, I1;
      if (S0 > 0.f) { I0 = 1.f / S0; } else { I0 = 0.f; M0 = 0.f; }
      if (S1 > 0.f) { I1 = 1.f / S1; } else { I1 = 0.f; M1 = 0.f; }
      param[j]           = make_float4(c10, M0, I0, 0.f);
      param[N_NODES + j] = make_float4(c11, M1, I1, 0.f);
    }
    __syncthreads();
  }
}

// exclusive prefix sum over 8192 column counts -> colptr, cursor
__global__ __launch_bounds__(256) void k_scan(
    const int* __restrict__ colcnt, int* __restrict__ colptr, int* __restrict__ cursor) {
  __shared__ int ssum[256];
  const int t = threadIdx.x;
  const int base = t * 32;
  int loc[32];
  int run = 0;
#pragma unroll
  for (int r = 0; r < 32; ++r) { loc[r] = run; run += colcnt[base + r]; }
  ssum[t] = run;
  __syncthreads();
  for (int d = 1; d < 256; d <<= 1) {
    int v = (t >= d) ? ssum[t - d] : 0;
    __syncthreads();
    ssum[t] += v;
    __syncthreads();
  }
  const int inc = ssum[t];
  const int ex = inc - run;
#pragma unroll
  for (int r = 0; r < 32; ++r) {
    int p = ex + loc[r];
    colptr[base + r] = p;
    cursor[base + r] = p;
  }
  if (t == 255) colptr[N_NODES] = inc;
}

// fill CSC edge list. One wave per row j; wave reads its 256 mask words
// coalesced; each lane drains its own word's bits with independent atomics.
__global__ __launch_bounds__(256) void k_fill(
    const unsigned* __restrict__ umask,
    int* __restrict__ cursor, int* __restrict__ edges) {
  const int j = blockIdx.x * 4 + (threadIdx.x >> 6);
  const int lane = threadIdx.x & 63;
#pragma unroll
  for (int c = 0; c < 4; ++c) {
    const int w = c * 64 + lane;
    unsigned m = umask[(size_t)j * 256 + w];
    while (m) {
      const int bpos = __builtin_ctz(m);
      m &= m - 1;
      const int i = w * 32 + bpos;
      const int pos = atomicAdd(&cursor[i], 1);
      edges[pos] = j;
    }
  }
}

// K3: one wave per output row i (lane = o). 4-edge batches for MLP.
__global__ __launch_bounds__(256) void k3_aggregate(
    const int* __restrict__ colptr, const int* __restrict__ edges,
    const float4* __restrict__ param, const float* __restrict__ c2,
    const float* __restrict__ HW, const float* __restrict__ b,
    float* __restrict__ out) {
  const int lane = threadIdx.x & 63;
  const int i = __builtin_amdgcn_readfirstlane(blockIdx.x * 4 + (threadIdx.x >> 6));
  const float c20 = c2[i];
  const float c21 = c2[N_NODES + i];
  int e = colptr[i];
  const int end = colptr[i + 1];
  float acc0 = 0.f, acc1 = 0.f;

  for (; e + 4 <= end; e += 4) {
    const int ja = edges[e + 0];
    const int jb = edges[e + 1];
    const int jc = edges[e + 2];
    const int jd = edges[e + 3];
    const float4 pa0 = param[ja], pa1 = param[N_NODES + ja];
    const float4 pb0 = param[jb], pb1 = param[N_NODES + jb];
    const float4 pc0 = param[jc], pc1 = param[N_NODES + jc];
    const float4 pd0 = param[jd], pd1 = param[N_NODES + jd];
    const float ha0 = HW[(size_t)ja * 64 + lane], ha1 = HW[(size_t)(N_NODES + ja) * 64 + lane];
    const float hb0 = HW[(size_t)jb * 64 + lane], hb1 = HW[(size_t)(N_NODES + jb) * 64 + lane];
    const float hc0 = HW[(size_t)jc * 64 + lane], hc1 = HW[(size_t)(N_NODES + jc) * 64 + lane];
    const float hd0 = HW[(size_t)jd * 64 + lane], hd1 = HW[(size_t)(N_NODES + jd) * 64 + lane];

    float v, w;
    v = pa0.x + c20; v = (v >= 0.f) ? v : 0.2f * v; w = __expf(v - pa0.y) * pa0.z; acc0 = fmaf(w, ha0, acc0);
    v = pa1.x + c21; v = (v >= 0.f) ? v : 0.2f * v; w = __expf(v - pa1.y) * pa1.z; acc1 = fmaf(w, ha1, acc1);
    v = pb0.x + c20; v = (v >= 0.f) ? v : 0.2f * v; w = __expf(v - pb0.y) * pb0.z; acc0 = fmaf(w, hb0, acc0);
    v = pb1.x + c21; v = (v >= 0.f) ? v : 0.2f * v; w = __expf(v - pb1.y) * pb1.z; acc1 = fmaf(w, hb1, acc1);
    v = pc0.x + c20; v = (v >= 0.f) ? v : 0.2f * v; w = __expf(v - pc0.y) * pc0.z; acc0 = fmaf(w, hc0, acc0);
    v = pc1.x + c21; v = (v >= 0.f) ? v : 0.2f * v; w = __expf(v - pc1.y) * pc1.z; acc1 = fmaf(w, hc1, acc1);
    v = pd0.x + c20; v = (v >= 0.f) ? v : 0.2f * v; w = __expf(v - pd0.y) * pd0.z; acc0 = fmaf(w, hd0, acc0);
    v = pd1.x + c21; v = (v >= 0.f) ? v : 0.2f * v; w = __expf(v - pd1.y) * pd1.z; acc1 = fmaf(w, hd1, acc1);
  }
  for (; e < end; ++e) {
    const int j = edges[e];
    const float4 p0 = param[j];
    const float4 p1 = param[N_NODES + j];
    float v0 = p0.x + c20; v0 = (v0 >= 0.f) ? v0 : 0.2f * v0;
    float w0 = __expf(v0 - p0.y) * p0.z;
    float v1 = p1.x + c21; v1 = (v1 >= 0.f) ? v1 : 0.2f * v1;
    float w1 = __expf(v1 - p1.y) * p1.z;
    acc0 = fmaf(w0, HW[(size_t)j * 64 + lane], acc0);
    acc1 = fmaf(w1, HW[(size_t)(N_NODES + j) * 64 + lane], acc1);
  }
  float r0 = fmaxf(acc0 + b[lane], 0.f);
  float r1 = fmaxf(acc1 + b[64 + lane], 0.f);
  out[(size_t)i * 128 + lane]      = r0;
  out[(size_t)i * 128 + 64 + lane] = r1;
}

extern "C" void kernel_launch(void* const* d_in, const int* in_sizes, int n_in,
                              void* d_out, int out_size, void* d_ws, size_t ws_size,
                              hipStream_t stream) {
  const float* H   = (const float*)d_in[0];
  const float* A   = (const float*)d_in[1];
  const int*   idx = (const int*)d_in[2];
  const float* W   = (const float*)d_in[3];
  const float* b   = (const float*)d_in[4];
  const float* a1  = (const float*)d_in[5];
  const float* a2  = (const float*)d_in[6];
  float* out = (float*)d_out;

  char* ws = (char*)d_ws;
  float*    HW     = (float*)(ws + 0);                    //  4,194,304 B
  float*    c1     = (float*)(ws + 4194304);              //     65,536 B
  float*    c2     = (float*)(ws + 4259840);              //     65,536 B
  float4*   param  = (float4*)(ws + 4325376);             //    262,144 B
  unsigned* umask  = (unsigned*)(ws + 4587520);           //  8,388,608 B
  int*      colcnt = (int*)(ws + 12976128);               //     32,768 B
  int*      colptr = (int*)(ws + 13008896);               //     36,864 B
  int*      cursor = (int*)(ws + 13045760);               //     32,768 B
  int*      edges  = (int*)(ws + 13078528);               //  8,388,608 B

  hipMemsetAsync(colcnt, 0, N_NODES * sizeof(int), stream);
  k1_hw<<<512, 256, 0, stream>>>(H, W, a1, a2, HW, c1, c2);
  k2_stats<<<N_NODES / 8, 256, 0, stream>>>(A, idx, c1, c2, umask, colcnt, param);
  k_scan<<<1, 256, 0, stream>>>(colcnt, colptr, cursor);
  k_fill<<<N_NODES / 4, 256, 0, stream>>>(umask, cursor, edges);
  k3_aggregate<<<N_NODES / 4, 256, 0, stream>>>(colptr, edges, param, c2, HW, b, out);
}

// Round 3
// 596.620 us; speedup vs baseline: 1.4835x; 1.1050x over previous
//
#include <hip/hip_runtime.h>

#define NN 8192
#define FD 512
#define CAP 256

// merge two online-softmax states (m, s)
__device__ __forceinline__ void smax_merge(float& m, float& s, float mo, float so) {
  float M = fmaxf(m, mo);
  if (M == -INFINITY) { m = -INFINITY; s = 0.f; return; }
  s = s * __expf(m - M) + so * __expf(mo - M);
  m = M;
}

__device__ __forceinline__ unsigned f2bf(float x) {  // RNE fp32 -> bf16 bits
  unsigned u = __float_as_uint(x);
  u += 0x7FFFu + ((u >> 16) & 1u);
  return u >> 16;
}

// K0: one-time check idx == arange -> flag (0 = fast path)
__global__ __launch_bounds__(256) void k0_check(
    const int* __restrict__ idx, int* __restrict__ flag) {
  const int t = blockIdx.x * 256 + threadIdx.x;   // 2048 threads, 1 int4 each
  int4 v = ((const int4*)idx)[t];
  const int base = t * 4;
  bool bad = (v.x != base) | (v.y != base + 1) | (v.z != base + 2) | (v.w != base + 3);
  if (__ballot(bad)) { if ((threadIdx.x & 63) == 0) atomicOr(flag, 1); }
}

// K1: HW[k,n,o] = sum_f H[n,f] W[k,f,o]  (stored packed bf16x2, k innermost)
//     c1[k,n] = HW.a1 ; c2[k,n] = HW.a2  (fp32)
__global__ __launch_bounds__(256) void k1_hw(
    const float* __restrict__ H, const float* __restrict__ W,
    const float* __restrict__ a1, const float* __restrict__ a2,
    unsigned short* __restrict__ hw2, float* __restrict__ c1, float* __restrict__ c2) {
  const int k    = blockIdx.x & 1;
  const int wv   = threadIdx.x >> 6;
  const int lane = threadIdx.x & 63;
  const int nbase = __builtin_amdgcn_readfirstlane((blockIdx.x >> 1) * 16 + wv * 4);
  const float* __restrict__ Wk = W + k * (FD * 64);
  float acc[4] = {0.f, 0.f, 0.f, 0.f};
  for (int f = 0; f < FD; f += 4) {
    float w0 = Wk[(f+0)*64 + lane];
    float w1 = Wk[(f+1)*64 + lane];
    float w2 = Wk[(f+2)*64 + lane];
    float w3 = Wk[(f+3)*64 + lane];
#pragma unroll
    for (int r = 0; r < 4; ++r) {
      float4 h = *(const float4*)(H + (size_t)(nbase + r) * FD + f);  // wave-uniform
      acc[r] = fmaf(h.x, w0, acc[r]);
      acc[r] = fmaf(h.y, w1, acc[r]);
      acc[r] = fmaf(h.z, w2, acc[r]);
      acc[r] = fmaf(h.w, w3, acc[r]);
    }
  }
  const float a1v = a1[k*64 + lane];
  const float a2v = a2[k*64 + lane];
#pragma unroll
  for (int r = 0; r < 4; ++r) {
    const int n = nbase + r;
    hw2[((size_t)n * 64 + lane) * 2 + k] = (unsigned short)f2bf(acc[r]);
    float t1 = acc[r] * a1v;
    float t2 = acc[r] * a2v;
#pragma unroll
    for (int off = 32; off; off >>= 1) {
      t1 += __shfl_down(t1, off);
      t2 += __shfl_down(t2, off);
    }
    if (lane == 0) { c1[k*NN + n] = t1; c2[k*NN + n] = t2; }
  }
}

// K2: one wave per row j. Fully coalesced A scan (lane reads float4 at
// col = g*256 + lane*4 -> 1KB/wave/instr). Online softmax (wave-level reduce,
// no LDS, no syncthreads). Nonzeros -> direct bucket edge write via colcnt atomic.
__global__ __launch_bounds__(256) void k2_stats(
    const float* __restrict__ A, const int* __restrict__ idx, const int* __restrict__ flag,
    const float* __restrict__ c1, const float* __restrict__ c2,
    int* __restrict__ colcnt, int* __restrict__ edges, float4* __restrict__ param) {
  const int wv = threadIdx.x >> 6, lane = threadIdx.x & 63;
  const int j = blockIdx.x * 4 + wv;
  const bool fast = (flag[0] == 0);  // uniform
  const float c10 = c1[j];
  const float c11 = c1[NN + j];
  const float* __restrict__ Arow = A + (size_t)j * NN;
  float m0 = -INFINITY, s0 = 0.f, m1 = -INFINITY, s1 = 0.f;

  for (int g = 0; g < 32; g += 8) {
    float4 a[8];
    if (fast) {
#pragma unroll
      for (int u = 0; u < 8; ++u)
        a[u] = *(const float4*)(Arow + (g + u) * 256 + lane * 4);
    } else {
#pragma unroll
      for (int u = 0; u < 8; ++u) {
        const int ib = (g + u) * 256 + lane * 4;
        a[u].x = Arow[idx[ib+0]];
        a[u].y = Arow[idx[ib+1]];
        a[u].z = Arow[idx[ib+2]];
        a[u].w = Arow[idx[ib+3]];
      }
    }
#pragma unroll
    for (int u = 0; u < 8; ++u) {
      const int ib = (g + u) * 256 + lane * 4;
      const float vals[4] = {a[u].x, a[u].y, a[u].z, a[u].w};
#pragma unroll
      for (int q = 0; q < 4; ++q) {
        if (vals[q] != 0.f) {
          const int i = ib + q;
          const int pos = atomicAdd(&colcnt[i], 1);
          if (pos < CAP) edges[(size_t)i * CAP + pos] = j;
          float v0 = c10 + c2[i];      v0 = (v0 >= 0.f) ? v0 : 0.2f * v0;
          float M = fmaxf(m0, v0);
          s0 = s0 * __expf(m0 - M) + __expf(v0 - M); m0 = M;
          float v1 = c11 + c2[NN + i]; v1 = (v1 >= 0.f) ? v1 : 0.2f * v1;
          M = fmaxf(m1, v1);
          s1 = s1 * __expf(m1 - M) + __expf(v1 - M); m1 = M;
        }
      }
    }
  }
#pragma unroll
  for (int off = 32; off; off >>= 1) {
    float mo = __shfl_down(m0, off), so = __shfl_down(s0, off);
    smax_merge(m0, s0, mo, so);
    mo = __shfl_down(m1, off); so = __shfl_down(s1, off);
    smax_merge(m1, s1, mo, so);
  }
  if (lane == 0) {
    float I0 = (s0 > 0.f) ? 1.f / s0 : 0.f; if (s0 <= 0.f) m0 = 0.f;
    float I1 = (s1 > 0.f) ? 1.f / s1 : 0.f; if (s1 <= 0.f) m1 = 0.f;
    param[j]      = make_float4(c10, m0, I0, 0.f);
    param[NN + j] = make_float4(c11, m1, I1, 0.f);
  }
}

// K3: one wave per output row i (lane = o). Gather bucket edges; one packed
// bf16x2 dword per edge covers both heads. Fused bias+ReLU+transpose.
__global__ __launch_bounds__(256) void k3_aggregate(
    const int* __restrict__ colcnt, const int* __restrict__ edges,
    const float4* __restrict__ param, const float* __restrict__ c2,
    const unsigned* __restrict__ hw2, const float* __restrict__ b,
    float* __restrict__ out) {
  const int lane = threadIdx.x & 63;
  const int i = __builtin_amdgcn_readfirstlane(blockIdx.x * 4 + (threadIdx.x >> 6));
  const float c20 = c2[i];
  const float c21 = c2[NN + i];
  const int cnt = min(colcnt[i], CAP);
  const int* __restrict__ eb = edges + (size_t)i * CAP;
  float acc0 = 0.f, acc1 = 0.f;
  int e = 0;
  for (; e + 4 <= cnt; e += 4) {
    const int ja = eb[e+0], jb = eb[e+1], jc = eb[e+2], jd = eb[e+3];
    const float4 pa0 = param[ja], pa1 = param[NN + ja];
    const float4 pb0 = param[jb], pb1 = param[NN + jb];
    const float4 pc0 = param[jc], pc1 = param[NN + jc];
    const float4 pd0 = param[jd], pd1 = param[NN + jd];
    const unsigned ua = hw2[ja * 64 + lane];
    const unsigned ub = hw2[jb * 64 + lane];
    const unsigned uc = hw2[jc * 64 + lane];
    const unsigned ud = hw2[jd * 64 + lane];
    float v, w;
    v = pa0.x + c20; v = (v >= 0.f) ? v : 0.2f*v; w = __expf(v - pa0.y) * pa0.z;
    acc0 = fmaf(w, __uint_as_float(ua << 16), acc0);
    v = pa1.x + c21; v = (v >= 0.f) ? v : 0.2f*v; w = __expf(v - pa1.y) * pa1.z;
    acc1 = fmaf(w, __uint_as_float(ua & 0xFFFF0000u), acc1);
    v = pb0.x + c20; v = (v >= 0.f) ? v : 0.2f*v; w = __expf(v - pb0.y) * pb0.z;
    acc0 = fmaf(w, __uint_as_float(ub << 16), acc0);
    v = pb1.x + c21; v = (v >= 0.f) ? v : 0.2f*v; w = __expf(v - pb1.y) * pb1.z;
    acc1 = fmaf(w, __uint_as_float(ub & 0xFFFF0000u), acc1);
    v = pc0.x + c20; v = (v >= 0.f) ? v : 0.2f*v; w = __expf(v - pc0.y) * pc0.z;
    acc0 = fmaf(w, __uint_as_float(uc << 16), acc0);
    v = pc1.x + c21; v = (v >= 0.f) ? v : 0.2f*v; w = __expf(v - pc1.y) * pc1.z;
    acc1 = fmaf(w, __uint_as_float(uc & 0xFFFF0000u), acc1);
    v = pd0.x + c20; v = (v >= 0.f) ? v : 0.2f*v; w = __expf(v - pd0.y) * pd0.z;
    acc0 = fmaf(w, __uint_as_float(ud << 16), acc0);
    v = pd1.x + c21; v = (v >= 0.f) ? v : 0.2f*v; w = __expf(v - pd1.y) * pd1.z;
    acc1 = fmaf(w, __uint_as_float(ud & 0xFFFF0000u), acc1);
  }
  for (; e < cnt; ++e) {
    const int j = eb[e];
    const float4 p0 = param[j], p1 = param[NN + j];
    const unsigned u = hw2[j * 64 + lane];
    float v0 = p0.x + c20; v0 = (v0 >= 0.f) ? v0 : 0.2f*v0;
    float w0 = __expf(v0 - p0.y) * p0.z;
    float v1 = p1.x + c21; v1 = (v1 >= 0.f) ? v1 : 0.2f*v1;
    float w1 = __expf(v1 - p1.y) * p1.z;
    acc0 = fmaf(w0, __uint_as_float(u << 16), acc0);
    acc1 = fmaf(w1, __uint_as_float(u & 0xFFFF0000u), acc1);
  }
  out[(size_t)i * 128 + lane]      = fmaxf(acc0 + b[lane], 0.f);
  out[(size_t)i * 128 + 64 + lane] = fmaxf(acc1 + b[64 + lane], 0.f);
}

extern "C" void kernel_launch(void* const* d_in, const int* in_sizes, int n_in,
                              void* d_out, int out_size, void* d_ws, size_t ws_size,
                              hipStream_t stream) {
  const float* H   = (const float*)d_in[0];
  const float* A   = (const float*)d_in[1];
  const int*   idx = (const int*)d_in[2];
  const float* W   = (const float*)d_in[3];
  const float* b   = (const float*)d_in[4];
  const float* a1  = (const float*)d_in[5];
  const float* a2  = (const float*)d_in[6];
  float* out = (float*)d_out;

  char* ws = (char*)d_ws;
  unsigned short* hw2    = (unsigned short*)(ws + 0);  //  2,097,152 B (bf16x2 packed)
  float*          c1     = (float*)(ws + 2097152);     //     65,536 B
  float*          c2     = (float*)(ws + 2162688);     //     65,536 B
  float4*         param  = (float4*)(ws + 2228224);    //    262,144 B
  int*            colcnt = (int*)(ws + 2490368);       //     32,768 B
  int*            flag   = (int*)(ws + 2523136);       //          4 B (contiguous w/ colcnt)
  int*            edges  = (int*)(ws + 2523392);       //  8,388,608 B (8192 x CAP)

  hipMemsetAsync(colcnt, 0, NN * sizeof(int) + sizeof(int), stream);  // colcnt + flag
  k0_check<<<8, 256, 0, stream>>>(idx, flag);
  k1_hw<<<1024, 256, 0, stream>>>(H, W, a1, a2, hw2, c1, c2);
  k2_stats<<<NN / 4, 256, 0, stream>>>(A, idx, flag, c1, c2, colcnt, edges, param);
  k3_aggregate<<<NN / 4, 256, 0, stream>>>(colcnt, edges, param, c2, (const unsigned*)hw2, b, out);
}